// Round 13
// baseline (111.119 us; speedup 1.0000x reference)
//
#include <hip/hip_runtime.h>
#include <hip/hip_bf16.h>

typedef unsigned int u32;
typedef unsigned short u16;
typedef unsigned char u8;
typedef _Float16 f16;
typedef __attribute__((ext_vector_type(2)))  _Float16 f16x2;
typedef __attribute__((ext_vector_type(8)))  _Float16 f16x8;
typedef __attribute__((ext_vector_type(16))) _Float16 f16x16;
typedef __attribute__((ext_vector_type(4))) float f32x4;

#define NSLOT   71
#define NCARD   71
#define ONEHOT  5041     // 71*71
#define INDIM   5048     // 71*71 + 7
#define D0      512
#define D1      256
#define D2      128
#define NACT    9

__device__ __forceinline__ u16 f2h_bits(float x) { f16 h = (f16)x; u16 r; __builtin_memcpy(&r, &h, 2); return r; }

// ---------------- prep: W0 -> f16, W1 -> W1T f16 (N x K), W2 -> W2T f16 ----------------
__global__ void prep_kernel(const float* __restrict__ W0, const float* __restrict__ W1,
                            const float* __restrict__ W2,
                            u16* __restrict__ W0h, u16* __restrict__ W1T, u16* __restrict__ W2T) {
    int i = blockIdx.x * 256 + threadIdx.x;
    const int n0 = INDIM * D0;      // 2,584,576
    const int n1 = D0 * D1;         // 131,072
    const int n2 = D1 * D2;         // 32,768
    if (i < n0) {
        W0h[i] = f2h_bits(W0[i]);
    } else if (i < n0 + n1) {
        int j = i - n0; int n = j >> 9, k = j & 511;     // W1T[n][k] = W1[k][n]
        W1T[j] = f2h_bits(W1[k * D1 + n]);
    } else if (i < n0 + n1 + n2) {
        int j = i - n0 - n1; int n = j >> 8, k = j & 255; // W2T[n][k] = W2[k][n]
        W2T[j] = f2h_bits(W2[k * D2 + n]);
    }
}

// ---------------- fused: gather layer0 (LDS-resident h0) + MFMA layers 1,2,p ----------------
// 512 blocks x 512 threads, 32 rows/block, LDS 63.5 KB -> 2 blocks/CU (16 waves).
// Rationale (R12): layer0 scatter is ~75% stall and invariant to bytes/occupancy/ILP;
// fusing lets co-resident waves' MFMA/LDS work fill those stalls, and kills the 16.8MB
// h0 write + re-read + one launch. h2buf overlays the dead idx/trl region (gather-only).
// Gather: thread = (row rg 0..31) x (cg 0..15), 32 cols = 64B/slot contiguous per thread.
// MLP body = R7-proven code with Abuf := h0buf (same [32][520] layout, 0 bank conflicts).
__global__ __launch_bounds__(512, 4)
void fused_kernel(const int* __restrict__ sidx, const float* __restrict__ trump,
                  const float* __restrict__ b0, const u16* __restrict__ W0h,
                  const u16* __restrict__ W1T, const u16* __restrict__ W2T,
                  const float* __restrict__ b1, const float* __restrict__ b2,
                  const float* __restrict__ Wp, const float* __restrict__ bp,
                  const int* __restrict__ legal, float* __restrict__ out) {
    __shared__ __align__(16) u8 smem[63552];
    u16*  h0buf = (u16*)(smem);             // [32][520] = 33280 B
    u16*  h1buf = (u16*)(smem + 33280);     // [32][264] = 16896 B
    float* wpb  = (float*)(smem + 50176);   // 1161 f32  =  4644 B
    u16*  h2buf = (u16*)(smem + 54832);     // [32][136] =  8704 B (overlays idxl/trl)
    u8*   idxl  = smem + 54832;             // [32][72]  =  2304 B (dead after gather)
    float* trl  = (float*)(smem + 57136);   // [32][7]   =   896 B (dead after gather)
    const int tid = threadIdx.x;
    const int r0 = blockIdx.x * 32;

    for (int i = tid; i < 32 * NSLOT; i += 512) {       // coalesced read: i = r*71+s
        int r = i / NSLOT, s = i - r * NSLOT;
        int v = sidx[r0 * NSLOT + i];
        v = v < 0 ? 0 : (v > NCARD - 1 ? NCARD - 1 : v);
        idxl[r * 72 + s] = (u8)v;
    }
    for (int i = tid; i < 32 * 7; i += 512)
        trl[i] = trump[r0 * 7 + i];
    for (int i = tid; i < D2 * NACT + NACT; i += 512)
        wpb[i] = (i < D2 * NACT) ? Wp[i] : bp[i - D2 * NACT];
    __syncthreads();

    // ---- gather phase: rows rg, cols [cg*32, cg*32+32) ----
    {
        const int rg = tid >> 4;             // 0..31
        const int cg = tid & 15;             // 0..15
        const int c0 = cg * 32;
        const u8* ixp = &idxl[rg * 72];
        const u16* Wc = W0h + c0;

        f16x16 acc0, acc1;
        {   // init with b0 + trump tail (rows 5041..5047 of W0)
            #pragma unroll
            for (int j = 0; j < 16; ++j) { acc0[j] = (f16)b0[c0 + j]; acc1[j] = (f16)b0[c0 + 16 + j]; }
            #pragma unroll
            for (int t = 0; t < 7; ++t) {
                const f16x16* wp = (const f16x16*)(Wc + (size_t)(ONEHOT + t) * D0);
                f16 tv = (f16)trl[rg * 7 + t];
                acc0 += wp[0] * tv;
                acc1 += wp[1] * tv;
            }
        }

#define LDP(s) ((const f16x16*)(Wc + (((size_t)((s) * NCARD + ixp[(s)])) << 9)))
        const f16x16* pa = LDP(0);
        const f16x16* pb = LDP(1);
        int s = 0;
        for (; s + 3 < NSLOT; s += 2) {      // exits with s = 68
            f16x16 a0 = pa[0], a1 = pa[1];
            f16x16 b0v = pb[0], b1v = pb[1];
            const f16x16* na = LDP(s + 2);
            const f16x16* nb = LDP(s + 3);
            __builtin_amdgcn_sched_barrier(0);
            acc0 += a0; acc1 += a1;
            acc0 += b0v; acc1 += b1v;
            pa = na; pb = nb;
        }
        {   // slots 68 (pa), 69 (pb), 70
            const f16x16* pc = LDP(70);
            acc0 += pa[0]; acc1 += pa[1];
            acc0 += pb[0]; acc1 += pb[1];
            acc0 += pc[0]; acc1 += pc[1];
        }
#undef LDP

        const f16x16 zero = {};
        f16x16 v0 = __builtin_elementwise_max(acc0, zero);   // ReLU, packed
        f16x16 v1 = __builtin_elementwise_max(acc1, zero);
        uint4* dst = (uint4*)&h0buf[rg * 520 + c0];
        dst[0] = ((const uint4*)&v0)[0];
        dst[1] = ((const uint4*)&v0)[1];
        dst[2] = ((const uint4*)&v1)[0];
        dst[3] = ((const uint4*)&v1)[1];
    }
    __syncthreads();

    const int w  = tid >> 6;     // wave 0..7
    const int l  = tid & 63;
    const int lc = l & 15;       // A row / B col / D col within 16-frag
    const int kg = l >> 4;       // 0..3

    // ---- layer 1: (32x512) @ (512x256), waves split N into 8 x 32 ----
    {
        const int n0 = w * 32;
        f32x4 a00 = {0.f,0.f,0.f,0.f}, a01 = a00, a10 = a00, a11 = a00;
        for (int kb = 0; kb < D0; kb += 32) {
            f16x8 av0 = *(const f16x8*)&h0buf[lc * 520 + kb + kg * 8];
            f16x8 av1 = *(const f16x8*)&h0buf[(lc + 16) * 520 + kb + kg * 8];
            f16x8 bv0 = *(const f16x8*)(W1T + (size_t)(n0 + lc) * D0 + kb + kg * 8);
            f16x8 bv1 = *(const f16x8*)(W1T + (size_t)(n0 + 16 + lc) * D0 + kb + kg * 8);
            a00 = __builtin_amdgcn_mfma_f32_16x16x32_f16(av0, bv0, a00, 0, 0, 0);
            a01 = __builtin_amdgcn_mfma_f32_16x16x32_f16(av0, bv1, a01, 0, 0, 0);
            a10 = __builtin_amdgcn_mfma_f32_16x16x32_f16(av1, bv0, a10, 0, 0, 0);
            a11 = __builtin_amdgcn_mfma_f32_16x16x32_f16(av1, bv1, a11, 0, 0, 0);
        }
        #pragma unroll
        for (int nb = 0; nb < 2; ++nb) {
            int col = n0 + nb * 16 + lc;
            float bias = b1[col];
            #pragma unroll
            for (int j = 0; j < 4; ++j) {
                f32x4 v0 = nb ? a01 : a00;
                f32x4 v1 = nb ? a11 : a10;
                h1buf[(kg * 4 + j) * 264 + col]        = f2h_bits(fmaxf(v0[j] + bias, 0.f));
                h1buf[(16 + kg * 4 + j) * 264 + col]   = f2h_bits(fmaxf(v1[j] + bias, 0.f));
            }
        }
    }
    __syncthreads();

    // ---- layer 2: (32x256) @ (256x128), waves split N into 8 x 16 ----
    {
        const int n0 = w * 16;
        f32x4 c0 = {0.f,0.f,0.f,0.f}, c1 = c0;
        for (int kb = 0; kb < D1; kb += 32) {
            f16x8 av0 = *(const f16x8*)&h1buf[lc * 264 + kb + kg * 8];
            f16x8 av1 = *(const f16x8*)&h1buf[(lc + 16) * 264 + kb + kg * 8];
            f16x8 bv  = *(const f16x8*)(W2T + (size_t)(n0 + lc) * D1 + kb + kg * 8);
            c0 = __builtin_amdgcn_mfma_f32_16x16x32_f16(av0, bv, c0, 0, 0, 0);
            c1 = __builtin_amdgcn_mfma_f32_16x16x32_f16(av1, bv, c1, 0, 0, 0);
        }
        int col = n0 + lc;
        float bias = b2[col];
        #pragma unroll
        for (int j = 0; j < 4; ++j) {
            h2buf[(kg * 4 + j) * 136 + col]      = f2h_bits(fmaxf(c0[j] + bias, 0.f));
            h2buf[(16 + kg * 4 + j) * 136 + col] = f2h_bits(fmaxf(c1[j] + bias, 0.f));
        }
    }
    __syncthreads();

    // ---- layer p + log_softmax: 128 threads, 4 threads per row (K split 4x32) ----
    if (tid < 128) {
        int r = tid >> 2, q = tid & 3;
        float part[NACT];
        #pragma unroll
        for (int a = 0; a < NACT; ++a) part[a] = 0.f;
        int kbase = q * 32;
        #pragma unroll
        for (int kk = 0; kk < 32; kk += 2) {
            u32 pr = *(const u32*)&h2buf[r * 136 + kbase + kk];
            f16x2 hp; __builtin_memcpy(&hp, &pr, 4);
            float x0 = (float)hp.x, x1 = (float)hp.y;
            #pragma unroll
            for (int a = 0; a < NACT; ++a)
                part[a] += x0 * wpb[(kbase + kk) * NACT + a] + x1 * wpb[(kbase + kk + 1) * NACT + a];
        }
        #pragma unroll
        for (int a = 0; a < NACT; ++a) {
            part[a] += __shfl_xor(part[a], 1, 64);
            part[a] += __shfl_xor(part[a], 2, 64);
        }
        if (q == 0) {
            int row = r0 + r;
            const int* mk = legal + (size_t)row * NACT;   // bool uploaded as 4-byte; nonzero = legal
            float lg[NACT]; float mx = -INFINITY;
            #pragma unroll
            for (int a = 0; a < NACT; ++a) {
                lg[a] = part[a] + wpb[D2 * NACT + a];
                if (mk[a] != 0 && lg[a] > mx) mx = lg[a];
            }
            float s = 0.f;
            #pragma unroll
            for (int a = 0; a < NACT; ++a) if (mk[a] != 0) s += __expf(lg[a] - mx);
            float lse = mx + __logf(s);
            #pragma unroll
            for (int a = 0; a < NACT; ++a)
                out[(size_t)row * NACT + a] = (mk[a] != 0) ? (lg[a] - lse) : -INFINITY;
        }
    }
}

extern "C" void kernel_launch(void* const* d_in, const int* in_sizes, int n_in,
                              void* d_out, int out_size, void* d_ws, size_t ws_size,
                              hipStream_t stream) {
    const int*   sidx  = (const int*)d_in[0];
    const float* trump = (const float*)d_in[1];
    const int*   legal = (const int*)d_in[2];
    const float* W0 = (const float*)d_in[3];
    const float* b0 = (const float*)d_in[4];
    const float* W1 = (const float*)d_in[5];
    const float* b1 = (const float*)d_in[6];
    const float* W2 = (const float*)d_in[7];
    const float* b2 = (const float*)d_in[8];
    const float* Wp = (const float*)d_in[9];
    const float* bp = (const float*)d_in[10];
    float* out = (float*)d_out;

    // ws layout (f16 elements): W0h | W1T | W2T   (h0 eliminated by fusion)
    u16* W0h  = (u16*)d_ws;
    u16* W1T  = W0h + (size_t)INDIM * D0;
    u16* W2T  = W1T + (size_t)D0 * D1;

    const int total = INDIM * D0 + D0 * D1 + D1 * D2;   // 2,748,416
    prep_kernel<<<(total + 255) / 256, 256, 0, stream>>>(W0, W1, W2, W0h, W1T, W2T);
    fused_kernel<<<512, 512, 0, stream>>>(sidx, trump, b0, W0h, W1T, W2T,
                                          b1, b2, Wp, bp, legal, out);
}

// Round 14
// 87.300 us; speedup vs baseline: 1.2728x; 1.2728x over previous
//
#include <hip/hip_runtime.h>
#include <hip/hip_bf16.h>

typedef unsigned int u32;
typedef unsigned short u16;
typedef unsigned char u8;
typedef _Float16 f16;
typedef __attribute__((ext_vector_type(2)))  _Float16 f16x2;
typedef __attribute__((ext_vector_type(8)))  _Float16 f16x8;
typedef __attribute__((ext_vector_type(16))) _Float16 f16x16;
typedef __attribute__((ext_vector_type(4))) float f32x4;

#define NSLOT   71
#define NCARD   71
#define ONEHOT  5041     // 71*71
#define INDIM   5048     // 71*71 + 7
#define D0      512
#define D1      256
#define D2      128
#define NACT    9

__device__ __forceinline__ u16 f2h_bits(float x) { f16 h = (f16)x; u16 r; __builtin_memcpy(&r, &h, 2); return r; }

// ---------------- prep: W0 -> f16 (vec4), W1 -> W1T f16 (N x K), W2 -> W2T f16 ----------------
__global__ void prep_kernel(const float* __restrict__ W0, const float* __restrict__ W1,
                            const float* __restrict__ W2,
                            u16* __restrict__ W0h, u16* __restrict__ W1T, u16* __restrict__ W2T) {
    int i = blockIdx.x * 256 + threadIdx.x;
    const int q0 = (INDIM * D0) / 4;    // 646,144 float4 groups
    const int n1 = D0 * D1;             // 131,072
    const int n2 = D1 * D2;             // 32,768
    if (i < q0) {
        float4 w = ((const float4*)W0)[i];
        ushort4 o;
        o.x = f2h_bits(w.x); o.y = f2h_bits(w.y);
        o.z = f2h_bits(w.z); o.w = f2h_bits(w.w);
        ((ushort4*)W0h)[i] = o;
    } else if (i < q0 + n1) {
        int j = i - q0; int n = j >> 9, k = j & 511;     // W1T[n][k] = W1[k][n]
        W1T[j] = f2h_bits(W1[k * D1 + n]);
    } else if (i < q0 + n1 + n2) {
        int j = i - q0 - n1; int n = j >> 8, k = j & 255; // W2T[n][k] = W2[k][n]
        W2T[j] = f2h_bits(W2[k * D2 + n]);
    }
}

// ---------------- layer 0: direct L1 gather-sum (R7-proven: 50.4us, FETCH 15MB) ----------------
// grid: 512 blocks = (chunk slow) x (ct = b&3 fast, XCD-aligned: R5 FETCH evidence).
// 128 rows/block, 512 threads = 64 rowgrp x 8 colgrp, 2 rows/thread, 2 blocks/CU.
__global__ __launch_bounds__(512)
void layer0_kernel(const int* __restrict__ sidx, const float* __restrict__ trump,
                   const float* __restrict__ b0, const u16* __restrict__ W0h,
                   u16* __restrict__ h0) {
    __shared__ u8 idxl[128 * NSLOT];     // [row][slot]
    __shared__ float trl[128 * 7];       // [row][t]
    const int tid = threadIdx.x;
    const int ct = blockIdx.x & 3;           // fast -> constant per XCD
    const int rbase = (blockIdx.x >> 2) * 128;

    for (int i = tid; i < 128 * NSLOT; i += 512) {      // coalesced: i = r*71+s
        int v = sidx[rbase * NSLOT + i];
        v = v < 0 ? 0 : (v > NCARD - 1 ? NCARD - 1 : v);
        idxl[i] = (u8)v;
    }
    for (int i = tid; i < 128 * 7; i += 512)
        trl[i] = trump[rbase * 7 + i];
    __syncthreads();

    const int rg = tid >> 3;                 // 0..63
    const int cg = tid & 7;                  // 0..7
    const int c0 = ct * 128 + cg * 16;       // col offset in [0,512)
    const u8* ix0 = &idxl[(rg * 2 + 0) * NSLOT];
    const u8* ix1 = &idxl[(rg * 2 + 1) * NSLOT];
    const u16* Wc = W0h + c0;                // column base

    f16x16 acc0, acc1;
    {   // init with b0 + trump tail (rows 5041..5047 of W0)
        f16x16 bias;
        #pragma unroll
        for (int j = 0; j < 16; ++j) bias[j] = (f16)b0[c0 + j];
        acc0 = bias; acc1 = bias;
        #pragma unroll
        for (int t = 0; t < 7; ++t) {
            f16x16 w16 = *(const f16x16*)(Wc + (size_t)(ONEHOT + t) * D0);
            acc0 += w16 * (f16)trl[(rg * 2 + 0) * 7 + t];
            acc1 += w16 * (f16)trl[(rg * 2 + 1) * 7 + t];
        }
    }

#define LD0(s) (*(const f16x16*)(Wc + ((size_t)(s) * NCARD + ix0[(s)]) * D0))
#define LD1(s) (*(const f16x16*)(Wc + ((size_t)(s) * NCARD + ix1[(s)]) * D0))

    f16x16 pa0 = LD0(0), pa1 = LD1(0);       // slot s   (even)
    f16x16 pb0 = LD0(1), pb1 = LD1(1);       // slot s+1 (odd)
    int s = 0;
    for (; s + 3 < NSLOT; s += 2) {          // exits with s = 68 (NSLOT = 71)
        f16x16 na0 = LD0(s + 2), na1 = LD1(s + 2);   // issue next pair FIRST
        f16x16 nb0 = LD0(s + 3), nb1 = LD1(s + 3);
        __builtin_amdgcn_sched_barrier(0);           // loads may not sink below
        acc0 += pa0; acc1 += pa1;                    // consume slots s, s+1
        acc0 += pb0; acc1 += pb1;
        pa0 = na0; pa1 = na1; pb0 = nb0; pb1 = nb1;  // rotate
    }
    // s = 68: pa = slot 68, pb = slot 69; slot 70 remains
    {
        f16x16 nc0 = LD0(70), nc1 = LD1(70);
        __builtin_amdgcn_sched_barrier(0);
        acc0 += pa0; acc1 += pa1;
        acc0 += pb0; acc1 += pb1;
        acc0 += nc0; acc1 += nc1;
    }
#undef LD0
#undef LD1

    const f16x16 zero = {};
    f16x16 v0 = __builtin_elementwise_max(acc0, zero);   // ReLU, packed
    f16x16 v1 = __builtin_elementwise_max(acc1, zero);
    uint4* dst0 = (uint4*)(h0 + (size_t)(rbase + rg * 2 + 0) * D0 + c0);
    uint4* dst1 = (uint4*)(h0 + (size_t)(rbase + rg * 2 + 1) * D0 + c0);
    dst0[0] = ((const uint4*)&v0)[0];
    dst0[1] = ((const uint4*)&v0)[1];
    dst1[0] = ((const uint4*)&v1)[0];
    dst1[1] = ((const uint4*)&v1)[1];
}

// ---------------- layers 1,2,p fused: per-block 32 rows, 1024 threads (16 waves) ----------------
// grid: 512 blocks. Layer1 N-split 16 waves x 16 cols (2 MFMA/k-step, half B-bytes/wave
// vs R7's 8x32); staging & barriers serviced by 2x wave parallelism. LDS 63.5 KB.
__global__ __launch_bounds__(1024)
void mlp_kernel(const u16* __restrict__ h0, const u16* __restrict__ W1T, const u16* __restrict__ W2T,
                const float* __restrict__ b1, const float* __restrict__ b2,
                const float* __restrict__ Wp, const float* __restrict__ bp,
                const int* __restrict__ legal, float* __restrict__ out) {
    __shared__ u16 Abuf[32 * 520];          // h0 tile, pad 8 (row 1040B)
    __shared__ u16 h1buf[32 * 264];         // pad 8 (528B)
    __shared__ u16 h2buf[32 * 136];         // pad 8 (272B)
    __shared__ float wpb[D2 * NACT + NACT]; // Wp + bp
    const int tid = threadIdx.x;
    const int r0 = blockIdx.x * 32;

    for (int i = tid; i < 2048; i += 1024) {            // 32 rows x 64 uint4
        int r = i >> 6, g = i & 63;
        uint4 v = *(const uint4*)(h0 + (size_t)(r0 + r) * D0 + g * 8);
        *(uint4*)&Abuf[r * 520 + g * 8] = v;
    }
    for (int i = tid; i < D2 * NACT + NACT; i += 1024)
        wpb[i] = (i < D2 * NACT) ? Wp[i] : bp[i - D2 * NACT];
    __syncthreads();

    const int w  = tid >> 6;     // wave 0..15
    const int l  = tid & 63;
    const int lc = l & 15;       // A row / B col / D col within 16-frag
    const int kg = l >> 4;       // 0..3

    // ---- layer 1: (32x512) @ (512x256), 16 waves x 16 N-cols ----
    {
        const int n0 = w * 16;
        f32x4 a0 = {0.f,0.f,0.f,0.f}, a1 = a0;
        const u16* b_base = W1T + (size_t)(n0 + lc) * D0;
        for (int kb = 0; kb < D0; kb += 32) {
            f16x8 av0 = *(const f16x8*)&Abuf[lc * 520 + kb + kg * 8];
            f16x8 av1 = *(const f16x8*)&Abuf[(lc + 16) * 520 + kb + kg * 8];
            f16x8 bv  = *(const f16x8*)(b_base + kb + kg * 8);
            a0 = __builtin_amdgcn_mfma_f32_16x16x32_f16(av0, bv, a0, 0, 0, 0);
            a1 = __builtin_amdgcn_mfma_f32_16x16x32_f16(av1, bv, a1, 0, 0, 0);
        }
        int col = n0 + lc;
        float bias = b1[col];
        #pragma unroll
        for (int j = 0; j < 4; ++j) {
            h1buf[(kg * 4 + j) * 264 + col]      = f2h_bits(fmaxf(a0[j] + bias, 0.f));
            h1buf[(16 + kg * 4 + j) * 264 + col] = f2h_bits(fmaxf(a1[j] + bias, 0.f));
        }
    }
    __syncthreads();

    // ---- layer 2: (32x256) @ (256x128), waves 0..7 x 16 N-cols ----
    if (w < 8) {
        const int n0 = w * 16;
        f32x4 c0 = {0.f,0.f,0.f,0.f}, c1 = c0;
        const u16* b_base = W2T + (size_t)(n0 + lc) * D1;
        for (int kb = 0; kb < D1; kb += 32) {
            f16x8 av0 = *(const f16x8*)&h1buf[lc * 264 + kb + kg * 8];
            f16x8 av1 = *(const f16x8*)&h1buf[(lc + 16) * 264 + kb + kg * 8];
            f16x8 bv  = *(const f16x8*)(b_base + kb + kg * 8);
            c0 = __builtin_amdgcn_mfma_f32_16x16x32_f16(av0, bv, c0, 0, 0, 0);
            c1 = __builtin_amdgcn_mfma_f32_16x16x32_f16(av1, bv, c1, 0, 0, 0);
        }
        int col = n0 + lc;
        float bias = b2[col];
        #pragma unroll
        for (int j = 0; j < 4; ++j) {
            h2buf[(kg * 4 + j) * 136 + col]      = f2h_bits(fmaxf(c0[j] + bias, 0.f));
            h2buf[(16 + kg * 4 + j) * 136 + col] = f2h_bits(fmaxf(c1[j] + bias, 0.f));
        }
    }
    __syncthreads();

    // ---- layer p + log_softmax: 128 threads, 4 threads per row (K split 4x32) ----
    if (tid < 128) {
        int r = tid >> 2, q = tid & 3;
        float part[NACT];
        #pragma unroll
        for (int a = 0; a < NACT; ++a) part[a] = 0.f;
        int kbase = q * 32;
        #pragma unroll
        for (int kk = 0; kk < 32; kk += 2) {
            u32 pr = *(const u32*)&h2buf[r * 136 + kbase + kk];
            f16x2 hp; __builtin_memcpy(&hp, &pr, 4);
            float x0 = (float)hp.x, x1 = (float)hp.y;
            #pragma unroll
            for (int a = 0; a < NACT; ++a)
                part[a] += x0 * wpb[(kbase + kk) * NACT + a] + x1 * wpb[(kbase + kk + 1) * NACT + a];
        }
        #pragma unroll
        for (int a = 0; a < NACT; ++a) {
            part[a] += __shfl_xor(part[a], 1, 64);
            part[a] += __shfl_xor(part[a], 2, 64);
        }
        if (q == 0) {
            int row = r0 + r;
            const int* mk = legal + (size_t)row * NACT;   // bool uploaded as 4-byte; nonzero = legal
            float lg[NACT]; float mx = -INFINITY;
            #pragma unroll
            for (int a = 0; a < NACT; ++a) {
                lg[a] = part[a] + wpb[D2 * NACT + a];
                if (mk[a] != 0 && lg[a] > mx) mx = lg[a];
            }
            float s = 0.f;
            #pragma unroll
            for (int a = 0; a < NACT; ++a) if (mk[a] != 0) s += __expf(lg[a] - mx);
            float lse = mx + __logf(s);
            #pragma unroll
            for (int a = 0; a < NACT; ++a)
                out[(size_t)row * NACT + a] = (mk[a] != 0) ? (lg[a] - lse) : -INFINITY;
        }
    }
}

extern "C" void kernel_launch(void* const* d_in, const int* in_sizes, int n_in,
                              void* d_out, int out_size, void* d_ws, size_t ws_size,
                              hipStream_t stream) {
    const int*   sidx  = (const int*)d_in[0];
    const float* trump = (const float*)d_in[1];
    const int*   legal = (const int*)d_in[2];
    const float* W0 = (const float*)d_in[3];
    const float* b0 = (const float*)d_in[4];
    const float* W1 = (const float*)d_in[5];
    const float* b1 = (const float*)d_in[6];
    const float* W2 = (const float*)d_in[7];
    const float* b2 = (const float*)d_in[8];
    const float* Wp = (const float*)d_in[9];
    const float* bp = (const float*)d_in[10];
    float* out = (float*)d_out;

    // ws layout (f16 elements): W0h | W1T | W2T | h0   -> 22.3 MB total
    u16* W0h  = (u16*)d_ws;
    u16* W1T  = W0h + (size_t)INDIM * D0;
    u16* W2T  = W1T + (size_t)D0 * D1;
    u16* h0   = W2T + (size_t)D1 * D2;

    const int nprep = (INDIM * D0) / 4 + D0 * D1 + D1 * D2;   // 809,984
    prep_kernel<<<(nprep + 255) / 256, 256, 0, stream>>>(W0, W1, W2, W0h, W1T, W2T);
    layer0_kernel<<<512, 512, 0, stream>>>(sidx, trump, b0, W0h, h0);
    mlp_kernel<<<512, 1024, 0, stream>>>(h0, W1T, W2T, b1, b2, Wp, bp, legal, out);
}

// Round 15
// 82.708 us; speedup vs baseline: 1.3435x; 1.0555x over previous
//
#include <hip/hip_runtime.h>
#include <hip/hip_bf16.h>

typedef unsigned int u32;
typedef unsigned short u16;
typedef unsigned char u8;
typedef _Float16 f16;
typedef __attribute__((ext_vector_type(2)))  _Float16 f16x2;
typedef __attribute__((ext_vector_type(8)))  _Float16 f16x8;
typedef __attribute__((ext_vector_type(16))) _Float16 f16x16;
typedef __attribute__((ext_vector_type(4))) float f32x4;

#define NSLOT   71
#define NCARD   71
#define ONEHOT  5041     // 71*71
#define INDIM   5048     // 71*71 + 7
#define D0      512
#define D1      256
#define D2      128
#define NACT    9

__device__ __forceinline__ u16 f2h_bits(float x) { f16 h = (f16)x; u16 r; __builtin_memcpy(&r, &h, 2); return r; }

// ---------------- prep: W0 -> f16 (vec4), W1 -> W1T f16 (N x K), W2 -> W2T f16 ----------------
__global__ void prep_kernel(const float* __restrict__ W0, const float* __restrict__ W1,
                            const float* __restrict__ W2,
                            u16* __restrict__ W0h, u16* __restrict__ W1T, u16* __restrict__ W2T) {
    int i = blockIdx.x * 256 + threadIdx.x;
    const int q0 = (INDIM * D0) / 4;    // 646,144 float4 groups
    const int n1 = D0 * D1;             // 131,072
    const int n2 = D1 * D2;             // 32,768
    if (i < q0) {
        float4 w = ((const float4*)W0)[i];
        ushort4 o;
        o.x = f2h_bits(w.x); o.y = f2h_bits(w.y);
        o.z = f2h_bits(w.z); o.w = f2h_bits(w.w);
        ((ushort4*)W0h)[i] = o;
    } else if (i < q0 + n1) {
        int j = i - q0; int n = j >> 9, k = j & 511;     // W1T[n][k] = W1[k][n]
        W1T[j] = f2h_bits(W1[k * D1 + n]);
    } else if (i < q0 + n1 + n2) {
        int j = i - q0 - n1; int n = j >> 8, k = j & 255; // W2T[n][k] = W2[k][n]
        W2T[j] = f2h_bits(W2[k * D2 + n]);
    }
}

// ---------------- layer 0: direct L1 gather-sum (R7-proven: ~52us, FETCH 15MB) ----------------
// grid: 512 blocks = (chunk slow) x (ct = b&3 fast, XCD-aligned: R5 FETCH evidence).
// 128 rows/block, 512 threads = 64 rowgrp x 8 colgrp, 2 rows/thread, 2 blocks/CU.
__global__ __launch_bounds__(512)
void layer0_kernel(const int* __restrict__ sidx, const float* __restrict__ trump,
                   const float* __restrict__ b0, const u16* __restrict__ W0h,
                   u16* __restrict__ h0) {
    __shared__ u8 idxl[128 * NSLOT];     // [row][slot]
    __shared__ float trl[128 * 7];       // [row][t]
    const int tid = threadIdx.x;
    const int ct = blockIdx.x & 3;           // fast -> constant per XCD
    const int rbase = (blockIdx.x >> 2) * 128;

    for (int i = tid; i < 128 * NSLOT; i += 512) {      // coalesced: i = r*71+s
        int v = sidx[rbase * NSLOT + i];
        v = v < 0 ? 0 : (v > NCARD - 1 ? NCARD - 1 : v);
        idxl[i] = (u8)v;
    }
    for (int i = tid; i < 128 * 7; i += 512)
        trl[i] = trump[rbase * 7 + i];
    __syncthreads();

    const int rg = tid >> 3;                 // 0..63
    const int cg = tid & 7;                  // 0..7
    const int c0 = ct * 128 + cg * 16;       // col offset in [0,512)
    const u8* ix0 = &idxl[(rg * 2 + 0) * NSLOT];
    const u8* ix1 = &idxl[(rg * 2 + 1) * NSLOT];
    const u16* Wc = W0h + c0;                // column base

    f16x16 acc0, acc1;
    {   // init with b0 + trump tail (rows 5041..5047 of W0)
        f16x16 bias;
        #pragma unroll
        for (int j = 0; j < 16; ++j) bias[j] = (f16)b0[c0 + j];
        acc0 = bias; acc1 = bias;
        #pragma unroll
        for (int t = 0; t < 7; ++t) {
            f16x16 w16 = *(const f16x16*)(Wc + (size_t)(ONEHOT + t) * D0);
            acc0 += w16 * (f16)trl[(rg * 2 + 0) * 7 + t];
            acc1 += w16 * (f16)trl[(rg * 2 + 1) * 7 + t];
        }
    }

#define LD0(s) (*(const f16x16*)(Wc + ((size_t)(s) * NCARD + ix0[(s)]) * D0))
#define LD1(s) (*(const f16x16*)(Wc + ((size_t)(s) * NCARD + ix1[(s)]) * D0))

    f16x16 pa0 = LD0(0), pa1 = LD1(0);       // slot s   (even)
    f16x16 pb0 = LD0(1), pb1 = LD1(1);       // slot s+1 (odd)
    int s = 0;
    for (; s + 3 < NSLOT; s += 2) {          // exits with s = 68 (NSLOT = 71)
        f16x16 na0 = LD0(s + 2), na1 = LD1(s + 2);   // issue next pair FIRST
        f16x16 nb0 = LD0(s + 3), nb1 = LD1(s + 3);
        __builtin_amdgcn_sched_barrier(0);           // loads may not sink below
        acc0 += pa0; acc1 += pa1;                    // consume slots s, s+1
        acc0 += pb0; acc1 += pb1;
        pa0 = na0; pa1 = na1; pb0 = nb0; pb1 = nb1;  // rotate
    }
    // s = 68: pa = slot 68, pb = slot 69; slot 70 remains
    {
        f16x16 nc0 = LD0(70), nc1 = LD1(70);
        __builtin_amdgcn_sched_barrier(0);
        acc0 += pa0; acc1 += pa1;
        acc0 += pb0; acc1 += pb1;
        acc0 += nc0; acc1 += nc1;
    }
#undef LD0
#undef LD1

    const f16x16 zero = {};
    f16x16 v0 = __builtin_elementwise_max(acc0, zero);   // ReLU, packed
    f16x16 v1 = __builtin_elementwise_max(acc1, zero);
    uint4* dst0 = (uint4*)(h0 + (size_t)(rbase + rg * 2 + 0) * D0 + c0);
    uint4* dst1 = (uint4*)(h0 + (size_t)(rbase + rg * 2 + 1) * D0 + c0);
    dst0[0] = ((const uint4*)&v0)[0];
    dst0[1] = ((const uint4*)&v0)[1];
    dst1[0] = ((const uint4*)&v1)[0];
    dst1[1] = ((const uint4*)&v1)[1];
}

// ---------------- layers 1,2,p fused: per-block 32 rows, MFMA 16x16x32 f16 ----------------
// grid: 512 blocks x 512 threads (8 waves).  LDS < 64KB.  (R7-proven body)
// Abuf staging via global_load_lds width=16 (async direct-to-LDS): R14 model showed the
// 4-loads/thread VGPR-roundtrip staging was ~15us of cross-XCD latency stall; gll removes
// the per-thread wait (single vmcnt drain at the barrier). One wave stages one 1024B h0
// row at wave-uniform LDS base (lane*16 auto-offset) -> padded [32][520] layout preserved.
__global__ __launch_bounds__(512)
void mlp_kernel(const u16* __restrict__ h0, const u16* __restrict__ W1T, const u16* __restrict__ W2T,
                const float* __restrict__ b1, const float* __restrict__ b2,
                const float* __restrict__ Wp, const float* __restrict__ bp,
                const int* __restrict__ legal, float* __restrict__ out) {
    __shared__ __align__(16) u16 Abuf[32 * 520];   // h0 tile, pad 8 (row 1040B)
    __shared__ u16 h1buf[32 * 264];         // pad 8 (528B)
    __shared__ u16 h2buf[32 * 136];         // pad 8 (272B)
    __shared__ float wpb[D2 * NACT + NACT]; // Wp + bp
    const int tid = threadIdx.x;
    const int r0 = blockIdx.x * 32;
    const int wv = tid >> 6;     // wave 0..7
    const int ln = tid & 63;

    #pragma unroll
    for (int k = 0; k < 4; ++k) {                       // wave wv stages rows wv+8k
        int r = wv + k * 8;
        const u32* gp = (const u32*)(h0 + (size_t)(r0 + r) * D0 + ln * 8);
        u32* lp = (u32*)&Abuf[r * 520];                 // wave-uniform base
        __builtin_amdgcn_global_load_lds((const __attribute__((address_space(1))) u32*)gp,
                                         (__attribute__((address_space(3))) u32*)lp,
                                         16, 0, 0);
    }
    for (int i = tid; i < D2 * NACT + NACT; i += 512)
        wpb[i] = (i < D2 * NACT) ? Wp[i] : bp[i - D2 * NACT];
    __syncthreads();   // drains vmcnt -> all staged rows complete

    const int w  = wv;
    const int l  = ln;
    const int lc = l & 15;       // A row / B col / D col within 16-frag
    const int kg = l >> 4;       // 0..3

    // ---- layer 1: (32x512) @ (512x256), waves split N into 8 x 32 ----
    {
        const int n0 = w * 32;
        f32x4 a00 = {0.f,0.f,0.f,0.f}, a01 = a00, a10 = a00, a11 = a00;
        for (int kb = 0; kb < D0; kb += 32) {
            f16x8 av0 = *(const f16x8*)&Abuf[lc * 520 + kb + kg * 8];
            f16x8 av1 = *(const f16x8*)&Abuf[(lc + 16) * 520 + kb + kg * 8];
            f16x8 bv0 = *(const f16x8*)(W1T + (size_t)(n0 + lc) * D0 + kb + kg * 8);
            f16x8 bv1 = *(const f16x8*)(W1T + (size_t)(n0 + 16 + lc) * D0 + kb + kg * 8);
            a00 = __builtin_amdgcn_mfma_f32_16x16x32_f16(av0, bv0, a00, 0, 0, 0);
            a01 = __builtin_amdgcn_mfma_f32_16x16x32_f16(av0, bv1, a01, 0, 0, 0);
            a10 = __builtin_amdgcn_mfma_f32_16x16x32_f16(av1, bv0, a10, 0, 0, 0);
            a11 = __builtin_amdgcn_mfma_f32_16x16x32_f16(av1, bv1, a11, 0, 0, 0);
        }
        #pragma unroll
        for (int nb = 0; nb < 2; ++nb) {
            int col = n0 + nb * 16 + lc;
            float bias = b1[col];
            #pragma unroll
            for (int j = 0; j < 4; ++j) {
                f32x4 v0 = nb ? a01 : a00;
                f32x4 v1 = nb ? a11 : a10;
                h1buf[(kg * 4 + j) * 264 + col]        = f2h_bits(fmaxf(v0[j] + bias, 0.f));
                h1buf[(16 + kg * 4 + j) * 264 + col]   = f2h_bits(fmaxf(v1[j] + bias, 0.f));
            }
        }
    }
    __syncthreads();

    // ---- layer 2: (32x256) @ (256x128), waves split N into 8 x 16 ----
    {
        const int n0 = w * 16;
        f32x4 c0 = {0.f,0.f,0.f,0.f}, c1 = c0;
        for (int kb = 0; kb < D1; kb += 32) {
            f16x8 av0 = *(const f16x8*)&h1buf[lc * 264 + kb + kg * 8];
            f16x8 av1 = *(const f16x8*)&h1buf[(lc + 16) * 264 + kb + kg * 8];
            f16x8 bv  = *(const f16x8*)(W2T + (size_t)(n0 + lc) * D1 + kb + kg * 8);
            c0 = __builtin_amdgcn_mfma_f32_16x16x32_f16(av0, bv, c0, 0, 0, 0);
            c1 = __builtin_amdgcn_mfma_f32_16x16x32_f16(av1, bv, c1, 0, 0, 0);
        }
        int col = n0 + lc;
        float bias = b2[col];
        #pragma unroll
        for (int j = 0; j < 4; ++j) {
            h2buf[(kg * 4 + j) * 136 + col]      = f2h_bits(fmaxf(c0[j] + bias, 0.f));
            h2buf[(16 + kg * 4 + j) * 136 + col] = f2h_bits(fmaxf(c1[j] + bias, 0.f));
        }
    }
    __syncthreads();

    // ---- layer p + log_softmax: 128 threads, 4 threads per row (K split 4x32) ----
    if (tid < 128) {
        int r = tid >> 2, q = tid & 3;
        float part[NACT];
        #pragma unroll
        for (int a = 0; a < NACT; ++a) part[a] = 0.f;
        int kbase = q * 32;
        #pragma unroll
        for (int kk = 0; kk < 32; kk += 2) {
            u32 pr = *(const u32*)&h2buf[r * 136 + kbase + kk];
            f16x2 hp; __builtin_memcpy(&hp, &pr, 4);
            float x0 = (float)hp.x, x1 = (float)hp.y;
            #pragma unroll
            for (int a = 0; a < NACT; ++a)
                part[a] += x0 * wpb[(kbase + kk) * NACT + a] + x1 * wpb[(kbase + kk + 1) * NACT + a];
        }
        #pragma unroll
        for (int a = 0; a < NACT; ++a) {
            part[a] += __shfl_xor(part[a], 1, 64);
            part[a] += __shfl_xor(part[a], 2, 64);
        }
        if (q == 0) {
            int row = r0 + r;
            const int* mk = legal + (size_t)row * NACT;   // bool uploaded as 4-byte; nonzero = legal
            float lg[NACT]; float mx = -INFINITY;
            #pragma unroll
            for (int a = 0; a < NACT; ++a) {
                lg[a] = part[a] + wpb[D2 * NACT + a];
                if (mk[a] != 0 && lg[a] > mx) mx = lg[a];
            }
            float s = 0.f;
            #pragma unroll
            for (int a = 0; a < NACT; ++a) if (mk[a] != 0) s += __expf(lg[a] - mx);
            float lse = mx + __logf(s);
            #pragma unroll
            for (int a = 0; a < NACT; ++a)
                out[(size_t)row * NACT + a] = (mk[a] != 0) ? (lg[a] - lse) : -INFINITY;
        }
    }
}

extern "C" void kernel_launch(void* const* d_in, const int* in_sizes, int n_in,
                              void* d_out, int out_size, void* d_ws, size_t ws_size,
                              hipStream_t stream) {
    const int*   sidx  = (const int*)d_in[0];
    const float* trump = (const float*)d_in[1];
    const int*   legal = (const int*)d_in[2];
    const float* W0 = (const float*)d_in[3];
    const float* b0 = (const float*)d_in[4];
    const float* W1 = (const float*)d_in[5];
    const float* b1 = (const float*)d_in[6];
    const float* W2 = (const float*)d_in[7];
    const float* b2 = (const float*)d_in[8];
    const float* Wp = (const float*)d_in[9];
    const float* bp = (const float*)d_in[10];
    float* out = (float*)d_out;

    // ws layout (f16 elements): W0h | W1T | W2T | h0   -> 22.3 MB total
    u16* W0h  = (u16*)d_ws;
    u16* W1T  = W0h + (size_t)INDIM * D0;
    u16* W2T  = W1T + (size_t)D0 * D1;
    u16* h0   = W2T + (size_t)D1 * D2;

    const int nprep = (INDIM * D0) / 4 + D0 * D1 + D1 * D2;   // 809,984
    prep_kernel<<<(nprep + 255) / 256, 256, 0, stream>>>(W0, W1, W2, W0h, W1T, W2T);
    layer0_kernel<<<512, 512, 0, stream>>>(sidx, trump, b0, W0h, h0);
    mlp_kernel<<<512, 512, 0, stream>>>(h0, W1T, W2T, b1, b2, Wp, bp, legal, out);
}